// Round 1
// baseline (113.129 us; speedup 1.0000x reference)
//
#include <hip/hip_runtime.h>
#include <math.h>

// Problem constants (from reference): B=32, N=8 objects, P0=64, P1=128, P2=64,
// C=128 out channels, V=2 vars -> K = 8*7 = 56 permutations,
// num_in = 64 + 2*128 + 2*64 = 448.
#define BATCH   32
#define NOBJ    8
#define P0      64
#define P1      128
#define P2      64
#define COUT    128
#define KPERM   56
#define ITOT    448        // concatenated predicate length
#define NBG     4          // batch groups per k  -> grid = 56*4 = 224 blocks
#define BG      8          // batches per block (2 halves of 4 per thread)

// ws layout (floats): tk[ITOT*COUT] then partial[KPERM*BATCH*COUT]
#define TK_ELEMS      (ITOT * COUT)          // 57344
#define PARTIAL_ELEMS (KPERM * BATCH * COUT) // 229376

__global__ __launch_bounds__(256) void prep_tanh(const float* __restrict__ kern,
                                                 float* __restrict__ tk) {
    int idx = blockIdx.x * 256 + threadIdx.x;
    if (idx < TK_ELEMS) tk[idx] = tanhf(kern[idx]);
}

// Grid: 56*NBG blocks, 256 threads. Block (k, bg) computes
// partial[k][b][c] = min_i ( x[b,k,i]*t[i,c] + 1 - t^2 ) for its 8 b's.
__global__ __launch_bounds__(256) void and_main(const float* __restrict__ nullary,
                                                const float* __restrict__ unary,
                                                const float* __restrict__ binary,
                                                const float* __restrict__ tk,
                                                float* __restrict__ partial) {
    // xs[i][b]: 448 x 8 floats = 14 KiB; [i][b] layout so 4 consecutive b's
    // are one broadcast ds_read_b128 per i-step.
    __shared__ float xs[ITOT * BG];

    const int blk = blockIdx.x;
    const int k   = blk / NBG;
    const int bg  = blk % NBG;
    const int bbase = bg * BG;

    // permutation k -> (a, bobj): for a in 0..7, b != a ascending
    const int a = k / (NOBJ - 1);
    const int r = k % (NOBJ - 1);
    const int bobj = r + (r >= a ? 1 : 0);
    // binary predicate second indices (N-1 indexing that skips the first obj)
    const int m0 = bobj - (bobj > a ? 1 : 0);  // pair (a, bobj)  == r
    const int m1 = a - (a > bobj ? 1 : 0);     // pair (bobj, a)

    const int tid = threadIdx.x;

    // ---- stage x[b][i] for this block's 8 batches into LDS ----
    for (int e = tid; e < ITOT * BG; e += 256) {
        const int i  = e >> 3;      // / BG
        const int bl = e & (BG - 1);
        const int b  = bbase + bl;
        float v;
        if (i < P0) {
            v = nullary[b * P0 + i];
        } else if (i < P0 + 2 * P1) {
            const int t2 = i - P0;
            const int vv = t2 >> 7;     // which var
            const int p  = t2 & (P1 - 1);
            const int n  = vv ? bobj : a;
            v = unary[(b * NOBJ + n) * P1 + p];
        } else {
            const int t2 = i - (P0 + 2 * P1);
            const int vv = t2 >> 6;
            const int p  = t2 & (P2 - 1);
            const int n  = vv ? bobj : a;
            const int m  = vv ? m1 : m0;
            v = binary[((b * NOBJ + n) * (NOBJ - 1) + m) * P2 + p];
        }
        xs[e] = v;
    }
    __syncthreads();

    const int c = tid & (COUT - 1);
    const int h = tid >> 7;         // 0/1 -> which 4 batches of the 8
    const int boff = h * 4;

    float acc0 = INFINITY, acc1 = INFINITY, acc2 = INFINITY, acc3 = INFINITY;

    const float* tkp = tk + c;
    const float4* xp = (const float4*)(xs) ;  // xs[i*8 + boff] -> float4

    #pragma unroll 4
    for (int i = 0; i < ITOT; ++i) {
        const float t  = tkp[i * COUT];
        const float bs = fmaf(-t, t, 1.0f);          // 1 - t^2
        const float4 x = xp[i * 2 + h];              // xs[i*8 + h*4 .. +3]
        acc0 = fminf(acc0, fmaf(x.x, t, bs));
        acc1 = fminf(acc1, fmaf(x.y, t, bs));
        acc2 = fminf(acc2, fmaf(x.z, t, bs));
        acc3 = fminf(acc3, fmaf(x.w, t, bs));
    }

    float* pp = partial + ((size_t)k * BATCH + bbase + boff) * COUT + c;
    pp[0 * COUT] = acc0;
    pp[1 * COUT] = acc1;
    pp[2 * COUT] = acc2;
    pp[3 * COUT] = acc3;
}

// out[b][c] = max over k of partial[k][b][c]
__global__ __launch_bounds__(128) void and_reduce(const float* __restrict__ partial,
                                                  float* __restrict__ out) {
    const int b = blockIdx.x;
    const int c = threadIdx.x;
    float mx = -INFINITY;
    #pragma unroll 8
    for (int k = 0; k < KPERM; ++k) {
        mx = fmaxf(mx, partial[((size_t)k * BATCH + b) * COUT + c]);
    }
    out[b * COUT + c] = mx;
}

extern "C" void kernel_launch(void* const* d_in, const int* in_sizes, int n_in,
                              void* d_out, int out_size, void* d_ws, size_t ws_size,
                              hipStream_t stream) {
    const float* nullary = (const float*)d_in[0];  // (32, 64)
    const float* unary   = (const float*)d_in[1];  // (32, 8, 128)
    const float* binary  = (const float*)d_in[2];  // (32, 8, 7, 64)
    const float* kern    = (const float*)d_in[3];  // (448, 128)
    float* out = (float*)d_out;                    // (32, 128)

    float* tk      = (float*)d_ws;
    float* partial = tk + TK_ELEMS;

    prep_tanh<<<(TK_ELEMS + 255) / 256, 256, 0, stream>>>(kern, tk);
    and_main<<<KPERM * NBG, 256, 0, stream>>>(nullary, unary, binary, tk, partial);
    and_reduce<<<BATCH, COUT, 0, stream>>>(partial, out);
}

// Round 2
// 82.644 us; speedup vs baseline: 1.3689x; 1.3689x over previous
//
#include <hip/hip_runtime.h>
#include <math.h>

// B=32, N=8, P0=64, P1=128, P2=64, C=128, V=2 -> K=56 perms, ITOT=448.
#define BATCH   32
#define NOBJ    8
#define P0      64
#define P1      128
#define P2      64
#define COUT    128
#define KPERM   56
#define ITOT    448
#define NBG     4          // batch groups of 8 -> main grid = 56*4 = 224 blocks
#define IC      16         // i-chunk unroll (448/16 = 28 chunks)

// ws layout (floats):
//   tk  [ITOT*COUT]            = 57344 f   (tanh(kernel))
//   X   [KPERM*8*ITOT*4]       = 802816 f  (gathered preds: [k][g4][i][j])
//   amax[BATCH*COUT]           = 4096 u32  (monotonic-encoded atomic max)
#define TK_ELEMS  (ITOT * COUT)
#define X_ELEMS   (KPERM * 8 * ITOT * 4)

__device__ __forceinline__ unsigned enc_f32(float f) {
    unsigned b = __float_as_uint(f);
    return (b & 0x80000000u) ? ~b : (b | 0x80000000u);
}

// grid 256 blocks x 256 thr:
//   blocks 0..223  : gather X for (k = blk/4, bg = blk%4)
//   blocks 224..255: tk = tanh(kernel)  (grid-stride, 57344 = 32*256*7)
//   blocks 224..239: zero amax (16*256 = 4096)
__global__ __launch_bounds__(256) void prep(const float* __restrict__ nullary,
                                            const float* __restrict__ unary,
                                            const float* __restrict__ binary,
                                            const float* __restrict__ kern,
                                            float* __restrict__ tk,
                                            float* __restrict__ X,
                                            unsigned* __restrict__ amax) {
    const int blk = blockIdx.x;
    const int tid = threadIdx.x;

    if (blk < KPERM * NBG) {
        const int k  = blk >> 2;
        const int bg = blk & 3;
        const int a = k / (NOBJ - 1);
        const int r = k % (NOBJ - 1);
        const int bobj = r + (r >= a ? 1 : 0);
        const int m0 = bobj - (bobj > a ? 1 : 0);  // pair (a, bobj)
        const int m1 = a - (a > bobj ? 1 : 0);     // pair (bobj, a)

        for (int e = tid; e < ITOT * 8; e += 256) {
            const int i  = e >> 3;
            const int lb = e & 7;
            const int b  = bg * 8 + lb;
            float v;
            if (i < P0) {
                v = nullary[b * P0 + i];
            } else if (i < P0 + 2 * P1) {
                const int t2 = i - P0;
                const int vv = t2 >> 7;
                const int p  = t2 & (P1 - 1);
                const int n  = vv ? bobj : a;
                v = unary[(b * NOBJ + n) * P1 + p];
            } else {
                const int t2 = i - (P0 + 2 * P1);
                const int vv = t2 >> 6;
                const int p  = t2 & (P2 - 1);
                const int n  = vv ? bobj : a;
                const int m  = vv ? m1 : m0;
                v = binary[((b * NOBJ + n) * (NOBJ - 1) + m) * P2 + p];
            }
            const int g = bg * 2 + (lb >> 2);   // batch-group of 4
            const int j = lb & 3;
            X[((k * 8 + g) * ITOT + i) * 4 + j] = v;
        }
    } else {
        const int tb = blk - KPERM * NBG;       // 0..31
        const int idx0 = tb * 256 + tid;
        #pragma unroll
        for (int it = 0; it < 7; ++it) {
            const int idx = idx0 + it * 8192;
            tk[idx] = tanhf(kern[idx]);
        }
        if (tb < 16) amax[idx0] = 0u;
    }
}

// grid 224 blocks x 256 thr: block (k = blk/4, bg = blk%4); c = tid&127,
// h = tid>>7 -> wave-uniform batch-group g = bg*2+h (4 batches per thread).
__global__ __launch_bounds__(256) void and_main(const float* __restrict__ tk,
                                                const float* __restrict__ X,
                                                unsigned* __restrict__ amax) {
    const int blk = blockIdx.x;
    const int k   = blk >> 2;
    const int bg  = blk & 3;
    const int tid = threadIdx.x;
    const int c   = tid & (COUT - 1);
    const int h   = tid >> 7;
    const int g   = bg * 2 + h;                 // uniform within each wave

    const int fbase = __builtin_amdgcn_readfirstlane((k * 8 + g) * ITOT);
    const float4* __restrict__ Xg = ((const float4*)X) + fbase;  // Xg[i] = x for 4 batches
    const float* __restrict__ tkp = tk + c;

    float acc0 = INFINITY, acc1 = INFINITY, acc2 = INFINITY, acc3 = INFINITY;

    for (int i0 = 0; i0 < ITOT; i0 += IC) {
        float  tv[IC];
        float4 xv[IC];
        #pragma unroll
        for (int u = 0; u < IC; ++u) tv[u] = tkp[(i0 + u) << 7];
        #pragma unroll
        for (int u = 0; u < IC; ++u) xv[u] = Xg[i0 + u];
        #pragma unroll
        for (int u = 0; u < IC; ++u) {
            const float t  = tv[u];
            const float bs = fmaf(-t, t, 1.0f);   // 1 - t^2
            acc0 = fminf(acc0, fmaf(xv[u].x, t, bs));
            acc1 = fminf(acc1, fmaf(xv[u].y, t, bs));
            acc2 = fminf(acc2, fmaf(xv[u].z, t, bs));
            acc3 = fminf(acc3, fmaf(xv[u].w, t, bs));
        }
    }

    // max over k via monotonic-encoded atomicMax; out[b][c], b = g*4+j
    unsigned* base = amax + (g * 4) * COUT + c;
    atomicMax(base + 0 * COUT, enc_f32(acc0));
    atomicMax(base + 1 * COUT, enc_f32(acc1));
    atomicMax(base + 2 * COUT, enc_f32(acc2));
    atomicMax(base + 3 * COUT, enc_f32(acc3));
}

// 16 blocks x 256 thr: decode amax -> out (4096 floats)
__global__ __launch_bounds__(256) void decode(const unsigned* __restrict__ amax,
                                              float* __restrict__ out) {
    const int idx = blockIdx.x * 256 + threadIdx.x;
    const unsigned u = amax[idx];
    const unsigned b = (u & 0x80000000u) ? (u ^ 0x80000000u) : ~u;
    out[idx] = __uint_as_float(b);
}

extern "C" void kernel_launch(void* const* d_in, const int* in_sizes, int n_in,
                              void* d_out, int out_size, void* d_ws, size_t ws_size,
                              hipStream_t stream) {
    const float* nullary = (const float*)d_in[0];  // (32, 64)
    const float* unary   = (const float*)d_in[1];  // (32, 8, 128)
    const float* binary  = (const float*)d_in[2];  // (32, 8, 7, 64)
    const float* kern    = (const float*)d_in[3];  // (448, 128)
    float* out = (float*)d_out;                    // (32, 128)

    float*    tk   = (float*)d_ws;
    float*    X    = tk + TK_ELEMS;
    unsigned* amax = (unsigned*)(X + X_ELEMS);

    prep<<<256, 256, 0, stream>>>(nullary, unary, binary, kern, tk, X, amax);
    and_main<<<KPERM * NBG, 256, 0, stream>>>(tk, X, amax);
    decode<<<16, 256, 0, stream>>>(amax, out);
}

// Round 3
// 79.087 us; speedup vs baseline: 1.4304x; 1.0450x over previous
//
#include <hip/hip_runtime.h>
#include <math.h>

// B=32, N=8, P0=64, P1=128, P2=64, C=128, V=2 -> K=56 perms, ITOT=448.
#define BATCH   32
#define NOBJ    8
#define P0      64
#define P1      128
#define P2      64
#define COUT    128
#define KPERM   56
#define ITOT    448
#define NBG     8          // batch-groups of 4 -> main grid = 56*8 = 448 blocks
#define NIH     4          // i-splits per block (448/4 = 112 i's per thread)
#define ISEG    (ITOT / NIH)
#define IC      16         // t-load chunk depth

// ws layout (u32/f32): amax[4096] | counter[1] | pad -> tk at +4352
#define AMAX_ELEMS 4096
#define TK_OFF     4352
#define TK_ELEMS   (ITOT * COUT)     // 57344

__device__ __forceinline__ unsigned enc_f32(float f) {
    unsigned b = __float_as_uint(f);
    return (b & 0x80000000u) ? ~b : (b | 0x80000000u);
}
__device__ __forceinline__ float dec_f32(unsigned u) {
    unsigned b = (u & 0x80000000u) ? (u ^ 0x80000000u) : ~u;
    return __uint_as_float(b);
}

// 224 blocks x 256 thr: tk = tanh(kernel); blocks 0..16 also zero amax+counter.
__global__ __launch_bounds__(256) void prep(const float* __restrict__ kern,
                                            float* __restrict__ tk,
                                            unsigned* __restrict__ amax) {
    const int idx = blockIdx.x * 256 + threadIdx.x;   // < 57344 exactly
    tk[idx] = tanhf(kern[idx]);
    if (idx < AMAX_ELEMS + 1) amax[idx] = 0u;          // amax + counter
}

// 448 blocks x 512 thr. Block (k = blk>>3, bg = blk&7) -> batches bg*4..+3.
// Thread (c = tid&127, ih = tid>>7) does i in [ih*112, ih*112+112).
__global__ __launch_bounds__(512) void and_main(const float* __restrict__ nullary,
                                                const float* __restrict__ unary,
                                                const float* __restrict__ binary,
                                                const float* __restrict__ tk,
                                                unsigned* __restrict__ amax,
                                                unsigned* __restrict__ counter,
                                                float* __restrict__ out) {
    __shared__ float4 xs[ITOT];        // xs[i] = x for the block's 4 batches
    __shared__ float4 pm[NIH][COUT];   // per-ih partial mins
    __shared__ unsigned lastflag;

    const int blk = blockIdx.x;
    const int k   = blk >> 3;
    const int bg  = blk & 7;
    const int tid = threadIdx.x;
    const int c   = tid & (COUT - 1);
    const int ih  = tid >> 7;          // uniform per wave

    // permutation k -> (a, bobj); binary second-index remap
    const int a = k / (NOBJ - 1);
    const int r = k % (NOBJ - 1);
    const int bobj = r + (r >= a ? 1 : 0);
    const int m0 = bobj - (bobj > a ? 1 : 0);   // pair (a, bobj)
    const int m1 = a - (a > bobj ? 1 : 0);      // pair (bobj, a)

    // ---- gather x[i][j] (4 batches) into LDS ----
    float* xsf = (float*)xs;
    for (int e = tid; e < ITOT * 4; e += 512) {
        const int i = e >> 2;
        const int j = e & 3;
        const int b = bg * 4 + j;
        float v;
        if (i < P0) {
            v = nullary[b * P0 + i];
        } else if (i < P0 + 2 * P1) {
            const int t2 = i - P0;
            const int vv = t2 >> 7;
            const int p  = t2 & (P1 - 1);
            const int n  = vv ? bobj : a;
            v = unary[(b * NOBJ + n) * P1 + p];
        } else {
            const int t2 = i - (P0 + 2 * P1);
            const int vv = t2 >> 6;
            const int p  = t2 & (P2 - 1);
            const int n  = vv ? bobj : a;
            const int m  = vv ? m1 : m0;
            v = binary[((b * NOBJ + n) * (NOBJ - 1) + m) * P2 + p];
        }
        xsf[e] = v;
    }
    __syncthreads();

    // ---- main loop over this thread's i-segment ----
    const float* __restrict__ tkp = tk + c;
    float acc0 = INFINITY, acc1 = INFINITY, acc2 = INFINITY, acc3 = INFINITY;

    const int ibase = ih * ISEG;
    for (int i0 = ibase; i0 < ibase + ISEG; i0 += IC) {
        float tv[IC];
        #pragma unroll
        for (int u = 0; u < IC; ++u) tv[u] = tkp[(i0 + u) << 7];
        #pragma unroll
        for (int u = 0; u < IC; ++u) {
            const float t  = tv[u];
            const float bs = fmaf(-t, t, 1.0f);    // 1 - t^2
            const float4 x = xs[i0 + u];           // LDS broadcast within wave
            acc0 = fminf(acc0, fmaf(x.x, t, bs));
            acc1 = fminf(acc1, fmaf(x.y, t, bs));
            acc2 = fminf(acc2, fmaf(x.z, t, bs));
            acc3 = fminf(acc3, fmaf(x.w, t, bs));
        }
    }

    // ---- combine min across the 4 ih-groups via LDS ----
    pm[ih][c] = make_float4(acc0, acc1, acc2, acc3);
    __syncthreads();

    if (ih == 0) {
        const float4 p0 = pm[0][c], p1 = pm[1][c], p2 = pm[2][c], p3 = pm[3][c];
        const float m0f = fminf(fminf(p0.x, p1.x), fminf(p2.x, p3.x));
        const float m1f = fminf(fminf(p0.y, p1.y), fminf(p2.y, p3.y));
        const float m2f = fminf(fminf(p0.z, p1.z), fminf(p2.z, p3.z));
        const float m3f = fminf(fminf(p0.w, p1.w), fminf(p2.w, p3.w));
        unsigned* base = amax + (bg * 4) * COUT + c;
        atomicMax(base + 0 * COUT, enc_f32(m0f));
        atomicMax(base + 1 * COUT, enc_f32(m1f));
        atomicMax(base + 2 * COUT, enc_f32(m2f));
        atomicMax(base + 3 * COUT, enc_f32(m3f));
    }

    // ---- last-block-done: final decode amax -> out ----
    __syncthreads();   // waits vmcnt drain: all this block's atomics complete
    if (tid == 0) {
        __threadfence();
        lastflag = (atomicAdd(counter, 1u) == (unsigned)(KPERM * NBG - 1));
    }
    __syncthreads();
    if (lastflag) {
        __threadfence();
        for (int e = tid; e < AMAX_ELEMS; e += 512) {
            const unsigned u = atomicAdd(amax + e, 0u);   // coherent read
            out[e] = dec_f32(u);
        }
    }
}

extern "C" void kernel_launch(void* const* d_in, const int* in_sizes, int n_in,
                              void* d_out, int out_size, void* d_ws, size_t ws_size,
                              hipStream_t stream) {
    const float* nullary = (const float*)d_in[0];  // (32, 64)
    const float* unary   = (const float*)d_in[1];  // (32, 8, 128)
    const float* binary  = (const float*)d_in[2];  // (32, 8, 7, 64)
    const float* kern    = (const float*)d_in[3];  // (448, 128)
    float* out = (float*)d_out;                    // (32, 128)

    unsigned* amax    = (unsigned*)d_ws;
    unsigned* counter = amax + AMAX_ELEMS;
    float*    tk      = (float*)d_ws + TK_OFF;

    prep<<<TK_ELEMS / 256, 256, 0, stream>>>(kern, tk, amax);
    and_main<<<KPERM * NBG, 512, 0, stream>>>(nullary, unary, binary, tk,
                                              amax, counter, out);
}